// Round 6
// baseline (99.552 us; speedup 1.0000x reference)
//
#include <hip/hip_runtime.h>
#include <math.h>

#define NCLS 80
#define BINS 17
#define REGMAX 16
#define NG 32
#define NB 16
#define KTOP 10
#define RAD 2.5f
#define NROWS 148        // 68 reg rows + 80 cls rows staged per tile
#define RPW 37           // rows per wave (148 / 4)
#define TILE 64

// ---------- workspace layout (bytes) ----------
#define WS_ACC   0
#define WS_NPOS  32
#define WS_DFLN  224
#define WS_ANYP  416
#define WS_CNT   608
#define WS_FB    640
#define NBLOCKS  (132 * 16)

// async global->LDS DMA, 4 bytes/lane, lane i lands at ldsbase + 4*i
__device__ __forceinline__ void dma4(const float* g, float* l) {
    __builtin_amdgcn_global_load_lds(
        (__attribute__((address_space(1))) void*)(g),
        (__attribute__((address_space(3))) void*)(l), 4, 0, 0);
}

// focal_bce with t=0: ce*0.75*p^2   (single exp + single log)
__device__ __forceinline__ float focal0(float x) {
    float e   = __expf(-fabsf(x));
    float inv = 1.0f / (1.0f + e);
    float p   = (x >= 0.0f) ? inv : e * inv;          // sigmoid(x)
    float ce  = fmaxf(x, 0.0f) + __logf(1.0f + e);
    return ce * 0.75f * p * p;
}

__device__ __forceinline__ float focal_t(float x, float t) {
    float e   = __expf(-fabsf(x));
    float inv = 1.0f / (1.0f + e);
    float p   = (x >= 0.0f) ? inv : e * inv;
    float ce  = fmaxf(x, 0.0f) - x * t + __logf(1.0f + e);
    float pt  = p * t + (1.0f - p) * (1.0f - t);
    float at  = 0.25f * t + 0.75f * (1.0f - t);
    float om  = 1.0f - pt;
    return ce * at * om * om;
}

// ---- prep: zero accumulators, exact any_pos via windowed scan, fallback ----
__global__ void k_prep(const float* __restrict__ gtb,
                       float* __restrict__ acc, float* __restrict__ npos,
                       float* __restrict__ dfln, int* __restrict__ anyp,
                       int* __restrict__ cnt, int* __restrict__ fb) {
    int lvl = blockIdx.x;
    int tid = threadIdx.x;               // 512 threads: b = tid>>5, g = tid&31
    int b = tid >> 5, g = tid & 31;
    int W = (lvl == 0) ? 80 : (lvl == 1 ? 40 : 20);
    float inv_s = (lvl == 0) ? 0.125f : (lvl == 1 ? 0.0625f : 0.03125f);
    if (lvl == 0) {
        if (tid < 2)  acc[tid] = 0.0f;
        if (tid < 48) { npos[tid] = 0.0f; dfln[tid] = 0.0f; }
        if (tid == 48) *cnt = 0;
    }
    __shared__ int s_any[NB];
    if (tid < NB) s_any[tid] = 0;
    __syncthreads();

    const float* bb = gtb + (b * NG + g) * 4;
    float x1 = bb[0] * inv_s, y1 = bb[1] * inv_s;
    float x2 = bb[2] * inv_s, y2 = bb[3] * inv_s;
    float gcx = (x1 + x2) * 0.5f, gcy = (y1 + y2) * 0.5f;
    // exact brute scan over a window that provably contains all positives
    int j0 = max((int)floorf(gcx) - 4, 0), j1 = min((int)floorf(gcx) + 4, W - 1);
    int i0 = max((int)floorf(gcy) - 4, 0), i1 = min((int)floorf(gcy) + 4, W - 1);
    bool any = false;
    for (int i = i0; i <= i1; ++i) {
        float cy = (float)i + 0.5f;
        for (int j = j0; j <= j1; ++j) {
            float cx = (float)j + 0.5f;
            bool m = (cx - x1 > 0.0f) && (cy - y1 > 0.0f) &&
                     (x2 - cx > 0.0f) && (y2 - cy > 0.0f) &&
                     (cx >= gcx - RAD) && (cx <= gcx + RAD) &&
                     (cy >= gcy - RAD) && (cy <= gcy + RAD);
            any = any || m;
        }
    }
    if (any) atomicOr(&s_any[b], 1);
    __syncthreads();
    if (g == 0) anyp[lvl * NB + b] = s_any[b];

    // fallback top-10 (essentially never taken)
    if (!s_any[b]) {
        float bd[KTOP]; int bi[KTOP];
        for (int t = 0; t < KTOP; ++t) { bd[t] = 3.0e38f; bi[t] = 0; }
        int HW = W * W;
        for (int p = 0; p < HW; ++p) {
            float cx = (float)(p % W) + 0.5f;
            float cy = (float)(p / W) + 0.5f;
            float dx = cx - gcx, dy = cy - gcy;
            float d = dx * dx + dy * dy;
            if (d < bd[KTOP - 1]) {
                int t = KTOP - 1;
                while (t > 0 && d < bd[t - 1]) { bd[t] = bd[t-1]; bi[t] = bi[t-1]; --t; }
                bd[t] = d; bi[t] = p;
            }
        }
        int* o = fb + ((lvl * NB + b) * NG + g) * KTOP;
        for (int t = 0; t < KTOP; ++t) o[t] = bi[t];
    }
}

// ---- main: 64-pt tiles, async LDS staging, all compute from LDS ----
__global__ __launch_bounds__(256) void k_main_f(
    const float* __restrict__ reg0, const float* __restrict__ cls0,
    const float* __restrict__ reg1, const float* __restrict__ cls1,
    const float* __restrict__ reg2, const float* __restrict__ cls2,
    const float* __restrict__ gtb,  const int* __restrict__ lab,
    const int* __restrict__ anyp,   const int* __restrict__ fb,
    float* __restrict__ acc, float* __restrict__ npos, float* __restrict__ dfln,
    int* __restrict__ cnt, float* __restrict__ out)
{
    int bx = blockIdx.x;
    int b  = blockIdx.y;
    int lvl, tix, W; const float *regp, *clsp; float inv_s;
    if (bx < 100)      { lvl = 0; tix = bx;       W = 80; regp = reg0; clsp = cls0; inv_s = 0.125f;   }
    else if (bx < 125) { lvl = 1; tix = bx - 100; W = 40; regp = reg1; clsp = cls1; inv_s = 0.0625f;  }
    else               { lvl = 2; tix = bx - 125; W = 20; regp = reg2; clsp = cls2; inv_s = 0.03125f; }
    int HW = W * W;
    int tile = tix * TILE;

    int lane = threadIdx.x & 63;
    int s    = threadIdx.x >> 6;
    int p    = tile + lane;
    bool v   = p < HW;
    int pc   = v ? p : 0;
    int ri = pc / W, ci = pc - ri * W;
    float cx = (float)ci + 0.5f, cy = (float)ri + 0.5f;

    __shared__ float s_stage[NROWS * 64];                // [row][64], bank = lane%32
    __shared__ float s_dv[4][64], s_lz[4][64], s_fz[4][64];
    __shared__ unsigned char s_ps[4][64];
    __shared__ float s_bx[NG][6];                        // x1,y1,x2,y2,gcx,gcy (scaled)
    __shared__ int   s_lab[NG];

    // --- stage boxes + labels (regular LDS writes) ---
    if (threadIdx.x < NG) {
        int g = threadIdx.x;
        float4 bb4 = *(const float4*)(gtb + (b * NG + g) * 4);
        float x1 = bb4.x * inv_s, y1 = bb4.y * inv_s;
        float x2 = bb4.z * inv_s, y2 = bb4.w * inv_s;
        s_bx[g][0] = x1; s_bx[g][1] = y1; s_bx[g][2] = x2; s_bx[g][3] = y2;
        s_bx[g][4] = (x1 + x2) * 0.5f; s_bx[g][5] = (y1 + y2) * 0.5f;
        s_lab[g] = lab[b * NG + g];
    }

    // --- issue ALL tile DMAs (148 rows x 256 B), fire-and-forget ---
    int pcl = min(tile + lane, HW - 1);   // clamp partial tiles in-bounds
#pragma unroll
    for (int t = 0; t < RPW; ++t) {
        int row = s * RPW + t;           // wave-uniform
        const float* src = (row < 68) ? regp + (b * 68 + row) * HW + pcl
                                      : clsp + (b * 80 + (row - 68)) * HW + pcl;
        dma4(src, s_stage + row * 64);
    }
    asm volatile("s_waitcnt vmcnt(0)" ::: "memory");
    __syncthreads();

    const float* st = s_stage;

    // --- softmax stats for distribution k = s ---
    {
        float xv[BINS];
#pragma unroll
        for (int t = 0; t < BINS; ++t) xv[t] = st[(s * BINS + t) * 64 + lane];
        float m = xv[0];
#pragma unroll
        for (int t = 1; t < BINS; ++t) m = fmaxf(m, xv[t]);
        float sum = 0.f, ex = 0.f;
#pragma unroll
        for (int t = 0; t < BINS; ++t) {
            float ee = __expf(xv[t] - m);
            sum += ee; ex += ee * (float)t;
        }
        s_dv[s][lane] = ex / sum;
        s_lz[s][lane] = __logf(sum) + m;
    }
    // --- focal0 over classes [s*20, s*20+20) ---
    {
        float fz = 0.f;
#pragma unroll
        for (int t = 0; t < 20; ++t)
            fz += focal0(st[(68 + s * 20 + t) * 64 + lane]);
        s_fz[s][lane] = fz;
    }
    __syncthreads();

    float dv[4], lz[4];
#pragma unroll
    for (int k = 0; k < 4; ++k) { dv[k] = s_dv[k][lane]; lz[k] = s_lz[k][lane]; }
    float fzs = s_fz[0][lane] + s_fz[1][lane] + s_fz[2][lane] + s_fz[3][lane];

    float px1 = cx - dv[0], py1 = cy - dv[1];
    float px2 = cx + dv[2], py2 = cy + dv[3];
    float pa = (px2 - px1) * (py2 - py1);

    bool anyb = anyp[lvl * NB + b] != 0;
    float bxa = 0.f, cla = 0.f, dfa = 0.f, np = 0.f;
    bool posi = false;

#define PROC_G(G, GEOM) do {                                             \
    float x1 = s_bx[G][0], y1 = s_bx[G][1];                              \
    float x2 = s_bx[G][2], y2 = s_bx[G][3];                              \
    float dl = cx - x1, dt = cy - y1, dr = x2 - cx, db = y2 - cy;        \
    bool m;                                                              \
    if (GEOM) {                                                          \
        float gx = s_bx[G][4], gy = s_bx[G][5];                          \
        m = (dl > 0.f) && (dt > 0.f) && (dr > 0.f) && (db > 0.f) &&      \
            (cx >= gx - RAD) && (cx <= gx + RAD) &&                      \
            (cy >= gy - RAD) && (cy <= gy + RAD);                        \
    } else {                                                             \
        const int* fbp = fb + ((lvl * NB + b) * NG + (G)) * KTOP;        \
        m = false;                                                       \
        _Pragma("unroll")                                                \
        for (int t = 0; t < KTOP; ++t) m = m || (fbp[t] == p);           \
    }                                                                    \
    m = m && v;                                                          \
    if (__any(m)) {                                                      \
        if (m) {                                                         \
            float ix1 = fmaxf(px1, x1), iy1 = fmaxf(py1, y1);            \
            float ix2 = fminf(px2, x2), iy2 = fminf(py2, y2);            \
            float iw = fmaxf(ix2 - ix1, 0.f), ih = fmaxf(iy2 - iy1, 0.f);\
            float inter = iw * ih;                                       \
            float ga = (x2 - x1) * (y2 - y1);                            \
            float iou = inter / (pa + ga - inter + 1e-6f);               \
            bxa += 1.f - iou; np += 1.f;                                 \
            float ltrb[4] = { dl, dt, dr, db };                          \
            _Pragma("unroll")                                            \
            for (int k = 0; k < 4; ++k) {                                \
                float tt = fminf(fmaxf(ltrb[k], 0.f), 15.9999f);         \
                float lf = floorf(tt); int lb = (int)lf;                 \
                int rb = lb + 1 > REGMAX ? REGMAX : lb + 1;              \
                float wl = (float)rb - tt, wr = tt - lf;                 \
                float xl = st[(k * BINS + lb) * 64 + lane];              \
                float xr = st[(k * BINS + rb) * 64 + lane];              \
                dfa -= (xl - lz[k]) * wl + (xr - lz[k]) * wr;            \
            }                                                            \
            int c = s_lab[G];                                            \
            float xat = st[(68 + c) * 64 + lane];                        \
            cla += fzs - focal0(xat) + focal_t(xat, iou);                \
        }                                                                \
    }                                                                    \
    posi = posi || m;                                                    \
} while (0)

    if (anyb) {
        // g-culling: row-range overlap test (conservative superset)
        int gg = lane & 31;
        float gy1 = s_bx[gg][1], gy2 = s_bx[gg][3], gcy = s_bx[gg][5];
        int r0 = tile / W;
        int r1 = min(tile + TILE - 1, HW - 1) / W;
        float cyLo = (float)r0 + 0.5f, cyHi = (float)r1 + 0.5f;
        bool act = (cyHi > gy1) && (gy2 > cyLo) &&
                   (cyHi >= gcy - RAD) && (cyLo <= gcy + RAD);
        unsigned long long bm = __ballot(act);
        unsigned m32 = (unsigned)(bm | (bm >> 32));
        int ord = 0;
        while (m32) {
            int g = __builtin_ctz(m32); m32 &= m32 - 1;
            if ((ord++ & 3) == s) PROC_G(g, true);
        }
    } else {
        for (int t = 0; t < 8; ++t) { int g = s * 8 + t; PROC_G(g, false); }
    }

    s_ps[s][lane] = posi;
    __syncthreads();
    if (s == 0) {
        int pg = s_ps[0][lane] | s_ps[1][lane] | s_ps[2][lane] | s_ps[3][lane];
        if (v && !pg) cla += fzs;     // cls_neg once per point
    }

    // --- block reduction: 4 values over 256 threads ---
    float v0 = bxa, v1 = cla, v2 = dfa, v3 = np;
    for (int off = 32; off > 0; off >>= 1) {
        v0 += __shfl_down(v0, off);
        v1 += __shfl_down(v1, off);
        v2 += __shfl_down(v2, off);
        v3 += __shfl_down(v3, off);
    }
    __shared__ float red[4][4];
    if (lane == 0) { red[s][0] = v0; red[s][1] = v1; red[s][2] = v2; red[s][3] = v3; }
    __syncthreads();
    if (threadIdx.x == 0) {
        float t0 = 0, t1 = 0, t2 = 0, t3 = 0;
        for (int w = 0; w < 4; ++w) {
            t0 += red[w][0]; t1 += red[w][1]; t2 += red[w][2]; t3 += red[w][3];
        }
        atomicAdd(&acc[0], t0);
        atomicAdd(&acc[1], t1);
        atomicAdd(&dfln[lvl * NB + b], t2);
        atomicAdd(&npos[lvl * NB + b], t3);
    }

    // --- last block finalizes the output ---
    __shared__ int s_tick;
    if (threadIdx.x == 0) {
        __threadfence();
        s_tick = atomicAdd(cnt, 1);
    }
    __syncthreads();
    if (s_tick == NBLOCKS - 1 && threadIdx.x < 64) {
        float vs = 0.f;
        if (lane < 48) {
            float n = atomicAdd(&npos[lane], 0.0f);   // coherent read
            float d = atomicAdd(&dfln[lane], 0.0f);
            if (n > 0.f) vs = d / (n * 4.0f);
        }
        for (int off = 32; off > 0; off >>= 1) vs += __shfl_down(vs, off);
        if (lane == 0) {
            float tbv = atomicAdd(&acc[0], 0.0f);
            float tcv = atomicAdd(&acc[1], 0.0f);
            out[0] = 7.5f * tbv + tcv + 1.5f * vs;
            out[1] = tbv; out[2] = tcv; out[3] = vs;
        }
    }
}

extern "C" void kernel_launch(void* const* d_in, const int* in_sizes, int n_in,
                              void* d_out, int out_size, void* d_ws, size_t ws_size,
                              hipStream_t stream) {
    const float* reg0 = (const float*)d_in[0];
    const float* cls0 = (const float*)d_in[1];
    const float* reg1 = (const float*)d_in[2];
    const float* cls1 = (const float*)d_in[3];
    const float* reg2 = (const float*)d_in[4];
    const float* cls2 = (const float*)d_in[5];
    const float* gtb  = (const float*)d_in[6];
    const int*   lab  = (const int*)d_in[7];
    float* out = (float*)d_out;

    char*  ws   = (char*)d_ws;
    float* acc  = (float*)(ws + WS_ACC);
    float* npos = (float*)(ws + WS_NPOS);
    float* dfln = (float*)(ws + WS_DFLN);
    int*   anyp = (int*)(ws + WS_ANYP);
    int*   cnt  = (int*)(ws + WS_CNT);
    int*   fb   = (int*)(ws + WS_FB);

    k_prep<<<3, 512, 0, stream>>>(gtb, acc, npos, dfln, anyp, cnt, fb);
    // L0: 100 tiles/batch, L1: 25, L2: 7  -> 132 x 16 blocks, 64 points/tile
    k_main_f<<<dim3(132, NB), 256, 0, stream>>>(reg0, cls0, reg1, cls1, reg2, cls2,
                                                gtb, lab, anyp, fb,
                                                acc, npos, dfln, cnt, out);
}

// Round 7
// 65.812 us; speedup vs baseline: 1.5127x; 1.5127x over previous
//
#include <hip/hip_runtime.h>
#include <math.h>

#define NCLS 80
#define BINS 17
#define REGMAX 16
#define NG 32
#define NB 16
#define KTOP 10
#define RAD 2.5f

// ---------- workspace layout (bytes) ----------
#define WS_ACC   0
#define WS_NPOS  32
#define WS_DFLN  224
#define WS_ANYP  416
#define WS_CNT   608
#define WS_FB    640
#define NBLOCKS  (67 * 16)

typedef float v2f __attribute__((ext_vector_type(2)));

// focal_bce with t=0: ce*0.75*p^2   (single exp + single log)
__device__ __forceinline__ float focal0(float x) {
    float e   = __expf(-fabsf(x));
    float inv = 1.0f / (1.0f + e);
    float p   = (x >= 0.0f) ? inv : e * inv;          // sigmoid(x)
    float ce  = fmaxf(x, 0.0f) + __logf(1.0f + e);
    return ce * 0.75f * p * p;
}

__device__ __forceinline__ float focal_t(float x, float t) {
    float e   = __expf(-fabsf(x));
    float inv = 1.0f / (1.0f + e);
    float p   = (x >= 0.0f) ? inv : e * inv;
    float ce  = fmaxf(x, 0.0f) - x * t + __logf(1.0f + e);
    float pt  = p * t + (1.0f - p) * (1.0f - t);
    float at  = 0.25f * t + 0.75f * (1.0f - t);
    float om  = 1.0f - pt;
    return ce * at * om * om;
}

// ---- prep: zero accumulators, exact any_pos via windowed scan, fallback ----
__global__ void k_prep(const float* __restrict__ gtb,
                       float* __restrict__ acc, float* __restrict__ npos,
                       float* __restrict__ dfln, int* __restrict__ anyp,
                       int* __restrict__ cnt, int* __restrict__ fb) {
    int lvl = blockIdx.x;
    int tid = threadIdx.x;               // 512 threads: b = tid>>5, g = tid&31
    int b = tid >> 5, g = tid & 31;
    int W = (lvl == 0) ? 80 : (lvl == 1 ? 40 : 20);
    float inv_s = (lvl == 0) ? 0.125f : (lvl == 1 ? 0.0625f : 0.03125f);
    if (lvl == 0) {
        if (tid < 2)  acc[tid] = 0.0f;
        if (tid < 48) { npos[tid] = 0.0f; dfln[tid] = 0.0f; }
        if (tid == 48) *cnt = 0;
    }
    __shared__ int s_any[NB];
    if (tid < NB) s_any[tid] = 0;
    __syncthreads();

    const float* bb = gtb + (b * NG + g) * 4;
    float x1 = bb[0] * inv_s, y1 = bb[1] * inv_s;
    float x2 = bb[2] * inv_s, y2 = bb[3] * inv_s;
    float gcx = (x1 + x2) * 0.5f, gcy = (y1 + y2) * 0.5f;
    int j0 = max((int)floorf(gcx) - 4, 0), j1 = min((int)floorf(gcx) + 4, W - 1);
    int i0 = max((int)floorf(gcy) - 4, 0), i1 = min((int)floorf(gcy) + 4, W - 1);
    bool any = false;
    for (int i = i0; i <= i1; ++i) {
        float cy = (float)i + 0.5f;
        for (int j = j0; j <= j1; ++j) {
            float cx = (float)j + 0.5f;
            bool m = (cx - x1 > 0.0f) && (cy - y1 > 0.0f) &&
                     (x2 - cx > 0.0f) && (y2 - cy > 0.0f) &&
                     (cx >= gcx - RAD) && (cx <= gcx + RAD) &&
                     (cy >= gcy - RAD) && (cy <= gcy + RAD);
            any = any || m;
        }
    }
    if (any) atomicOr(&s_any[b], 1);
    __syncthreads();
    if (g == 0) anyp[lvl * NB + b] = s_any[b];

    if (!s_any[b]) {
        float bd[KTOP]; int bi[KTOP];
        for (int t = 0; t < KTOP; ++t) { bd[t] = 3.0e38f; bi[t] = 0; }
        int HW = W * W;
        for (int p = 0; p < HW; ++p) {
            float cx = (float)(p % W) + 0.5f;
            float cy = (float)(p / W) + 0.5f;
            float dx = cx - gcx, dy = cy - gcy;
            float d = dx * dx + dy * dy;
            if (d < bd[KTOP - 1]) {
                int t = KTOP - 1;
                while (t > 0 && d < bd[t - 1]) { bd[t] = bd[t-1]; bi[t] = bi[t-1]; --t; }
                bd[t] = d; bi[t] = p;
            }
        }
        int* o = fb + ((lvl * NB + b) * NG + g) * KTOP;
        for (int t = 0; t < KTOP; ++t) o[t] = bi[t];
    }
}

// ---- main: 128-pt tiles, 4 slice-waves, ASM-batched loads (forced MLP) ----
__global__ __launch_bounds__(256, 3) void k_main_f(
    const float* __restrict__ reg0, const float* __restrict__ cls0,
    const float* __restrict__ reg1, const float* __restrict__ cls1,
    const float* __restrict__ reg2, const float* __restrict__ cls2,
    const float* __restrict__ gtb,  const int* __restrict__ lab,
    const int* __restrict__ anyp,   const int* __restrict__ fb,
    float* __restrict__ acc, float* __restrict__ npos, float* __restrict__ dfln,
    int* __restrict__ cnt, float* __restrict__ out)
{
    int bx = blockIdx.x;
    int b  = blockIdx.y;
    int lvl, tix, W; const float *regp, *clsp; float inv_s;
    if (bx < 50)      { lvl = 0; tix = bx;      W = 80; regp = reg0; clsp = cls0; inv_s = 0.125f;   }
    else if (bx < 63) { lvl = 1; tix = bx - 50; W = 40; regp = reg1; clsp = cls1; inv_s = 0.0625f;  }
    else              { lvl = 2; tix = bx - 63; W = 20; regp = reg2; clsp = cls2; inv_s = 0.03125f; }
    int HW = W * W;
    int tile = tix * 128;

    int lane = threadIdx.x & 63;
    int s    = threadIdx.x >> 6;
    int q0   = tile + 2 * lane;
    bool v   = q0 < HW;                  // HW even -> q0+1 also valid when v
    int pc   = v ? q0 : 0;
    int ri0  = pc / W, ci0 = pc - ri0 * W;
    float cx0 = (float)ci0 + 0.5f, cy0 = (float)ri0 + 0.5f;
    int ci1 = ci0 + 1, ri1 = ri0; if (ci1 == W) { ci1 = 0; ri1 = ri0 + 1; }
    float cx1 = (float)ci1 + 0.5f, cy1 = (float)ri1 + 0.5f;

    int qc2 = min(q0, HW - 2);           // in-bounds base for the dwordx2 loads
    int base_r = (b * 4 * BINS) * HW + pc;
    int base_c = (b * NCLS) * HW + pc;

    __shared__ float s_dv[4][128], s_lz[4][128], s_fz[4][128];
    __shared__ unsigned char s_ps[4][128];
    __shared__ float s_bx[NG][6];
    __shared__ int   s_lab[NG];

    // --- issue BOTH load batches via inline asm: all 37 loads in flight ---
    v2f r[BINS], c[20];
    {
        unsigned long long a1 = (unsigned long long)(regp + (size_t)(b * 68 + s * BINS) * HW + qc2);
        unsigned long long a2 = (unsigned long long)(clsp + (size_t)(b * 80 + s * 20) * HW + qc2);
        unsigned long long st = (unsigned long long)HW * 4ull;
        asm volatile(
            "global_load_dwordx2 %0, %[a], off\n\t"
            "v_lshl_add_u64 %[a], %[a], 0, %[st]\n\t"
            "global_load_dwordx2 %1, %[a], off\n\t"
            "v_lshl_add_u64 %[a], %[a], 0, %[st]\n\t"
            "global_load_dwordx2 %2, %[a], off\n\t"
            "v_lshl_add_u64 %[a], %[a], 0, %[st]\n\t"
            "global_load_dwordx2 %3, %[a], off\n\t"
            "v_lshl_add_u64 %[a], %[a], 0, %[st]\n\t"
            "global_load_dwordx2 %4, %[a], off\n\t"
            "v_lshl_add_u64 %[a], %[a], 0, %[st]\n\t"
            "global_load_dwordx2 %5, %[a], off\n\t"
            "v_lshl_add_u64 %[a], %[a], 0, %[st]\n\t"
            "global_load_dwordx2 %6, %[a], off\n\t"
            "v_lshl_add_u64 %[a], %[a], 0, %[st]\n\t"
            "global_load_dwordx2 %7, %[a], off\n\t"
            "v_lshl_add_u64 %[a], %[a], 0, %[st]\n\t"
            "global_load_dwordx2 %8, %[a], off\n\t"
            "v_lshl_add_u64 %[a], %[a], 0, %[st]\n\t"
            "global_load_dwordx2 %9, %[a], off\n\t"
            "v_lshl_add_u64 %[a], %[a], 0, %[st]\n\t"
            "global_load_dwordx2 %10, %[a], off\n\t"
            "v_lshl_add_u64 %[a], %[a], 0, %[st]\n\t"
            "global_load_dwordx2 %11, %[a], off\n\t"
            "v_lshl_add_u64 %[a], %[a], 0, %[st]\n\t"
            "global_load_dwordx2 %12, %[a], off\n\t"
            "v_lshl_add_u64 %[a], %[a], 0, %[st]\n\t"
            "global_load_dwordx2 %13, %[a], off\n\t"
            "v_lshl_add_u64 %[a], %[a], 0, %[st]\n\t"
            "global_load_dwordx2 %14, %[a], off\n\t"
            "v_lshl_add_u64 %[a], %[a], 0, %[st]\n\t"
            "global_load_dwordx2 %15, %[a], off\n\t"
            "v_lshl_add_u64 %[a], %[a], 0, %[st]\n\t"
            "global_load_dwordx2 %16, %[a], off"
            : "=&v"(r[0]), "=&v"(r[1]), "=&v"(r[2]), "=&v"(r[3]), "=&v"(r[4]),
              "=&v"(r[5]), "=&v"(r[6]), "=&v"(r[7]), "=&v"(r[8]), "=&v"(r[9]),
              "=&v"(r[10]), "=&v"(r[11]), "=&v"(r[12]), "=&v"(r[13]),
              "=&v"(r[14]), "=&v"(r[15]), "=&v"(r[16]), [a] "+v"(a1)
            : [st] "v"(st)
            : "memory");
        asm volatile(
            "global_load_dwordx2 %0, %[a], off\n\t"
            "v_lshl_add_u64 %[a], %[a], 0, %[st]\n\t"
            "global_load_dwordx2 %1, %[a], off\n\t"
            "v_lshl_add_u64 %[a], %[a], 0, %[st]\n\t"
            "global_load_dwordx2 %2, %[a], off\n\t"
            "v_lshl_add_u64 %[a], %[a], 0, %[st]\n\t"
            "global_load_dwordx2 %3, %[a], off\n\t"
            "v_lshl_add_u64 %[a], %[a], 0, %[st]\n\t"
            "global_load_dwordx2 %4, %[a], off\n\t"
            "v_lshl_add_u64 %[a], %[a], 0, %[st]\n\t"
            "global_load_dwordx2 %5, %[a], off\n\t"
            "v_lshl_add_u64 %[a], %[a], 0, %[st]\n\t"
            "global_load_dwordx2 %6, %[a], off\n\t"
            "v_lshl_add_u64 %[a], %[a], 0, %[st]\n\t"
            "global_load_dwordx2 %7, %[a], off\n\t"
            "v_lshl_add_u64 %[a], %[a], 0, %[st]\n\t"
            "global_load_dwordx2 %8, %[a], off\n\t"
            "v_lshl_add_u64 %[a], %[a], 0, %[st]\n\t"
            "global_load_dwordx2 %9, %[a], off\n\t"
            "v_lshl_add_u64 %[a], %[a], 0, %[st]\n\t"
            "global_load_dwordx2 %10, %[a], off\n\t"
            "v_lshl_add_u64 %[a], %[a], 0, %[st]\n\t"
            "global_load_dwordx2 %11, %[a], off\n\t"
            "v_lshl_add_u64 %[a], %[a], 0, %[st]\n\t"
            "global_load_dwordx2 %12, %[a], off\n\t"
            "v_lshl_add_u64 %[a], %[a], 0, %[st]\n\t"
            "global_load_dwordx2 %13, %[a], off\n\t"
            "v_lshl_add_u64 %[a], %[a], 0, %[st]\n\t"
            "global_load_dwordx2 %14, %[a], off\n\t"
            "v_lshl_add_u64 %[a], %[a], 0, %[st]\n\t"
            "global_load_dwordx2 %15, %[a], off\n\t"
            "v_lshl_add_u64 %[a], %[a], 0, %[st]\n\t"
            "global_load_dwordx2 %16, %[a], off\n\t"
            "v_lshl_add_u64 %[a], %[a], 0, %[st]\n\t"
            "global_load_dwordx2 %17, %[a], off\n\t"
            "v_lshl_add_u64 %[a], %[a], 0, %[st]\n\t"
            "global_load_dwordx2 %18, %[a], off\n\t"
            "v_lshl_add_u64 %[a], %[a], 0, %[st]\n\t"
            "global_load_dwordx2 %19, %[a], off"
            : "=&v"(c[0]), "=&v"(c[1]), "=&v"(c[2]), "=&v"(c[3]), "=&v"(c[4]),
              "=&v"(c[5]), "=&v"(c[6]), "=&v"(c[7]), "=&v"(c[8]), "=&v"(c[9]),
              "=&v"(c[10]), "=&v"(c[11]), "=&v"(c[12]), "=&v"(c[13]),
              "=&v"(c[14]), "=&v"(c[15]), "=&v"(c[16]), "=&v"(c[17]),
              "=&v"(c[18]), "=&v"(c[19]), [a] "+v"(a2)
            : [st] "v"(st)
            : "memory");
    }

    // --- stage boxes + labels (wave 0 only; its loads retire behind ours) ---
    if (threadIdx.x < NG) {
        int g = threadIdx.x;
        float4 bb4 = *(const float4*)(gtb + (b * NG + g) * 4);
        float x1 = bb4.x * inv_s, y1 = bb4.y * inv_s;
        float x2 = bb4.z * inv_s, y2 = bb4.w * inv_s;
        s_bx[g][0] = x1; s_bx[g][1] = y1; s_bx[g][2] = x2; s_bx[g][3] = y2;
        s_bx[g][4] = (x1 + x2) * 0.5f; s_bx[g][5] = (y1 + y2) * 0.5f;
        s_lab[g] = lab[b * NG + g];
    }

    // --- wait for the reg batch only (cls batch still in flight) ---
    asm volatile("s_waitcnt vmcnt(20)" ::: "memory");
    __builtin_amdgcn_sched_barrier(0);

    // softmax stats for distribution k = s (both points)
    {
        float m0 = r[0].x, m1 = r[0].y;
#pragma unroll
        for (int t = 1; t < BINS; ++t) { m0 = fmaxf(m0, r[t].x); m1 = fmaxf(m1, r[t].y); }
        float sa = 0.f, ea = 0.f, sb = 0.f, eb = 0.f;
#pragma unroll
        for (int t = 0; t < BINS; ++t) {
            float a = __expf(r[t].x - m0), cc = __expf(r[t].y - m1);
            sa += a; ea += a * (float)t; sb += cc; eb += cc * (float)t;
        }
        s_dv[s][2*lane]   = ea / sa;  s_lz[s][2*lane]   = __logf(sa) + m0;
        s_dv[s][2*lane+1] = eb / sb;  s_lz[s][2*lane+1] = __logf(sb) + m1;
    }

    // --- wait for the cls batch, then focal0 over 20 classes ---
    asm volatile("s_waitcnt vmcnt(0)" ::: "memory");
    __builtin_amdgcn_sched_barrier(0);
    {
        float fz0 = 0.f, fz1 = 0.f;
#pragma unroll
        for (int t = 0; t < 20; ++t) { fz0 += focal0(c[t].x); fz1 += focal0(c[t].y); }
        s_fz[s][2*lane] = fz0; s_fz[s][2*lane+1] = fz1;
    }
    __syncthreads();

    float dv0[4], lz0v[4], dv1[4], lz1v[4];
#pragma unroll
    for (int k = 0; k < 4; ++k) {
        dv0[k] = s_dv[k][2*lane];   lz0v[k] = s_lz[k][2*lane];
        dv1[k] = s_dv[k][2*lane+1]; lz1v[k] = s_lz[k][2*lane+1];
    }
    float fzs0 = s_fz[0][2*lane]   + s_fz[1][2*lane]   + s_fz[2][2*lane]   + s_fz[3][2*lane];
    float fzs1 = s_fz[0][2*lane+1] + s_fz[1][2*lane+1] + s_fz[2][2*lane+1] + s_fz[3][2*lane+1];

    float px1_0 = cx0 - dv0[0], py1_0 = cy0 - dv0[1];
    float px2_0 = cx0 + dv0[2], py2_0 = cy0 + dv0[3];
    float pa0 = (px2_0 - px1_0) * (py2_0 - py1_0);
    float px1_1 = cx1 - dv1[0], py1_1 = cy1 - dv1[1];
    float px2_1 = cx1 + dv1[2], py2_1 = cy1 + dv1[3];
    float pa1 = (px2_1 - px1_1) * (py2_1 - py1_1);

    bool anyb = anyp[lvl * NB + b] != 0;
    float bxa = 0.f, cla = 0.f, dfa = 0.f, np = 0.f;
    bool posi0 = false, posi1 = false;

#define HEAVY(G, CX, CY, DL, DT, DR, DB, PX1, PY1, PX2, PY2, PA, LZ, FZS, OFF) do { \
    float ix1 = fmaxf(PX1, x1), iy1 = fmaxf(PY1, y1);                    \
    float ix2 = fminf(PX2, x2), iy2 = fminf(PY2, y2);                    \
    float iw = fmaxf(ix2 - ix1, 0.f), ih = fmaxf(iy2 - iy1, 0.f);        \
    float inter = iw * ih;                                               \
    float ga = (x2 - x1) * (y2 - y1);                                    \
    float iou = inter / (PA + ga - inter + 1e-6f);                       \
    bxa += 1.f - iou; np += 1.f;                                         \
    float ltrb[4] = { DL, DT, DR, DB };                                  \
    _Pragma("unroll")                                                    \
    for (int k = 0; k < 4; ++k) {                                        \
        float tt = fminf(fmaxf(ltrb[k], 0.f), 15.9999f);                 \
        float lf = floorf(tt); int lb = (int)lf;                         \
        int rb = lb + 1 > REGMAX ? REGMAX : lb + 1;                      \
        float wl = (float)rb - tt, wr = tt - lf;                         \
        float xl = regp[base_r + OFF + (k * BINS + lb) * HW];            \
        float xr = regp[base_r + OFF + (k * BINS + rb) * HW];            \
        dfa -= (xl - LZ[k]) * wl + (xr - LZ[k]) * wr;                    \
    }                                                                    \
    int cc2 = s_lab[G];                                                  \
    float xat = clsp[base_c + OFF + cc2 * HW];                           \
    cla += FZS - focal0(xat) + focal_t(xat, iou);                        \
} while (0)

#define PROC_G(G, GEOM) do {                                             \
    float x1 = s_bx[G][0], y1 = s_bx[G][1];                              \
    float x2 = s_bx[G][2], y2 = s_bx[G][3];                              \
    float dl0 = cx0 - x1, dt0 = cy0 - y1, dr0 = x2 - cx0, db0 = y2 - cy0;\
    float dl1 = cx1 - x1, dt1 = cy1 - y1, dr1 = x2 - cx1, db1 = y2 - cy1;\
    bool m0, m1;                                                         \
    if (GEOM) {                                                          \
        float gx = s_bx[G][4], gy = s_bx[G][5];                          \
        m0 = (dl0 > 0.f) && (dt0 > 0.f) && (dr0 > 0.f) && (db0 > 0.f) && \
             (cx0 >= gx - RAD) && (cx0 <= gx + RAD) &&                   \
             (cy0 >= gy - RAD) && (cy0 <= gy + RAD);                     \
        m1 = (dl1 > 0.f) && (dt1 > 0.f) && (dr1 > 0.f) && (db1 > 0.f) && \
             (cx1 >= gx - RAD) && (cx1 <= gx + RAD) &&                   \
             (cy1 >= gy - RAD) && (cy1 <= gy + RAD);                     \
    } else {                                                             \
        const int* fbp = fb + ((lvl * NB + b) * NG + (G)) * KTOP;        \
        m0 = false; m1 = false;                                          \
        _Pragma("unroll")                                                \
        for (int t = 0; t < KTOP; ++t) {                                 \
            int f = fbp[t]; m0 = m0 || (f == q0); m1 = m1 || (f == q0+1);\
        }                                                                \
    }                                                                    \
    m0 = m0 && v; m1 = m1 && v;                                          \
    if (__any(m0 || m1)) {                                               \
        if (m0) HEAVY((G), cx0, cy0, dl0, dt0, dr0, db0,                 \
                      px1_0, py1_0, px2_0, py2_0, pa0, lz0v, fzs0, 0);   \
        if (m1) HEAVY((G), cx1, cy1, dl1, dt1, dr1, db1,                 \
                      px1_1, py1_1, px2_1, py2_1, pa1, lz1v, fzs1, 1);   \
    }                                                                    \
    posi0 = posi0 || m0; posi1 = posi1 || m1;                            \
} while (0)

    if (anyb) {
        int gg = lane & 31;
        float gy1 = s_bx[gg][1], gy2 = s_bx[gg][3], gcy = s_bx[gg][5];
        int r0 = tile / W;
        int r1 = min(tile + 127, HW - 1) / W;
        float cyLo = (float)r0 + 0.5f, cyHi = (float)r1 + 0.5f;
        bool act = (cyHi > gy1) && (gy2 > cyLo) &&
                   (cyHi >= gcy - RAD) && (cyLo <= gcy + RAD);
        unsigned long long bm = __ballot(act);
        unsigned m32 = (unsigned)(bm | (bm >> 32));
        int ord = 0;
        while (m32) {
            int g = __builtin_ctz(m32); m32 &= m32 - 1;
            if ((ord++ & 3) == s) PROC_G(g, true);
        }
    } else {
        for (int t = 0; t < 8; ++t) { int g = s * 8 + t; PROC_G(g, false); }
    }

    s_ps[s][2*lane] = posi0; s_ps[s][2*lane+1] = posi1;
    __syncthreads();
    if (s == 0) {
        int pg0 = s_ps[0][2*lane] | s_ps[1][2*lane] | s_ps[2][2*lane] | s_ps[3][2*lane];
        int pg1 = s_ps[0][2*lane+1] | s_ps[1][2*lane+1] | s_ps[2][2*lane+1] | s_ps[3][2*lane+1];
        if (v && !pg0) cla += fzs0;
        if (v && !pg1) cla += fzs1;
    }

    // --- block reduction: 4 values over 256 threads ---
    float v0 = bxa, v1 = cla, v2 = dfa, v3 = np;
    for (int off = 32; off > 0; off >>= 1) {
        v0 += __shfl_down(v0, off);
        v1 += __shfl_down(v1, off);
        v2 += __shfl_down(v2, off);
        v3 += __shfl_down(v3, off);
    }
    __shared__ float red[4][4];
    if (lane == 0) { red[s][0] = v0; red[s][1] = v1; red[s][2] = v2; red[s][3] = v3; }
    __syncthreads();
    if (threadIdx.x == 0) {
        float t0 = 0, t1 = 0, t2 = 0, t3 = 0;
        for (int w = 0; w < 4; ++w) {
            t0 += red[w][0]; t1 += red[w][1]; t2 += red[w][2]; t3 += red[w][3];
        }
        atomicAdd(&acc[0], t0);
        atomicAdd(&acc[1], t1);
        atomicAdd(&dfln[lvl * NB + b], t2);
        atomicAdd(&npos[lvl * NB + b], t3);
    }

    // --- last block finalizes the output ---
    __shared__ int s_tick;
    if (threadIdx.x == 0) {
        __threadfence();
        s_tick = atomicAdd(cnt, 1);
    }
    __syncthreads();
    if (s_tick == NBLOCKS - 1 && threadIdx.x < 64) {
        float vs = 0.f;
        if (lane < 48) {
            float n = atomicAdd(&npos[lane], 0.0f);   // coherent read
            float d = atomicAdd(&dfln[lane], 0.0f);
            if (n > 0.f) vs = d / (n * 4.0f);
        }
        for (int off = 32; off > 0; off >>= 1) vs += __shfl_down(vs, off);
        if (lane == 0) {
            float tbv = atomicAdd(&acc[0], 0.0f);
            float tcv = atomicAdd(&acc[1], 0.0f);
            out[0] = 7.5f * tbv + tcv + 1.5f * vs;
            out[1] = tbv; out[2] = tcv; out[3] = vs;
        }
    }
}

extern "C" void kernel_launch(void* const* d_in, const int* in_sizes, int n_in,
                              void* d_out, int out_size, void* d_ws, size_t ws_size,
                              hipStream_t stream) {
    const float* reg0 = (const float*)d_in[0];
    const float* cls0 = (const float*)d_in[1];
    const float* reg1 = (const float*)d_in[2];
    const float* cls1 = (const float*)d_in[3];
    const float* reg2 = (const float*)d_in[4];
    const float* cls2 = (const float*)d_in[5];
    const float* gtb  = (const float*)d_in[6];
    const int*   lab  = (const int*)d_in[7];
    float* out = (float*)d_out;

    char*  ws   = (char*)d_ws;
    float* acc  = (float*)(ws + WS_ACC);
    float* npos = (float*)(ws + WS_NPOS);
    float* dfln = (float*)(ws + WS_DFLN);
    int*   anyp = (int*)(ws + WS_ANYP);
    int*   cnt  = (int*)(ws + WS_CNT);
    int*   fb   = (int*)(ws + WS_FB);

    k_prep<<<3, 512, 0, stream>>>(gtb, acc, npos, dfln, anyp, cnt, fb);
    // L0: 50 tiles/batch, L1: 13, L2: 4  -> 67 x 16 blocks, 128 points/tile
    k_main_f<<<dim3(67, NB), 256, 0, stream>>>(reg0, cls0, reg1, cls1, reg2, cls2,
                                               gtb, lab, anyp, fb,
                                               acc, npos, dfln, cnt, out);
}